// Round 1
// baseline (730.711 us; speedup 1.0000x reference)
//
#include <hip/hip_runtime.h>
#include <hip/hip_bf16.h>

#define NN 2048
#define DD 64
#define BHH 32

typedef __attribute__((ext_vector_type(8))) short bf16x8;
typedef __attribute__((ext_vector_type(4))) float f32x4;

__device__ __forceinline__ unsigned short f2b(float f) {
    __hip_bfloat16 h = __float2bfloat16(f);
    return __builtin_bit_cast(unsigned short, h);
}

// ---------- prep: q,k -> bf16(2x-1), row-major [bh][n][d] ----------
__global__ void prep_qk(const float4* __restrict__ q, const float4* __restrict__ k,
                        ushort4* __restrict__ qo, ushort4* __restrict__ ko) {
    int i = blockIdx.x * 256 + threadIdx.x;   // exactly (B*H*N*D)/4 threads
    float4 a = q[i], b = k[i];
    ushort4 qa, kb;
    qa.x = f2b(2.f*a.x - 1.f); qa.y = f2b(2.f*a.y - 1.f);
    qa.z = f2b(2.f*a.z - 1.f); qa.w = f2b(2.f*a.w - 1.f);
    kb.x = f2b(2.f*b.x - 1.f); kb.y = f2b(2.f*b.y - 1.f);
    kb.z = f2b(2.f*b.z - 1.f); kb.w = f2b(2.f*b.w - 1.f);
    qo[i] = qa; ko[i] = kb;
}

// ---------- prep: v -> bf16 transposed [bh][d][n] ----------
__global__ void prep_v(const float* __restrict__ v, unsigned short* __restrict__ vt) {
    __shared__ float tile[64][65];
    int bh = blockIdx.x >> 5, jt = blockIdx.x & 31;
    int t = threadIdx.x;
    const float* src = v + ((size_t)bh * NN + jt * 64) * DD;
#pragma unroll
    for (int h = 0; h < 4; ++h) {
        int cc = t + h * 256;            // 1024 float4 chunks
        int row = cc >> 4, c4 = cc & 15;
        float4 f = *(const float4*)(src + row * DD + c4 * 4);
        tile[row][c4*4+0] = f.x; tile[row][c4*4+1] = f.y;
        tile[row][c4*4+2] = f.z; tile[row][c4*4+3] = f.w;
    }
    __syncthreads();
    unsigned short* dst = vt + (size_t)bh * DD * NN + jt * 64;
#pragma unroll
    for (int h = 0; h < 2; ++h) {
        int cc = t + h * 256;            // 512 chunks of 8 bf16
        int d = cc >> 3, c8 = cc & 7;
        unsigned int w0 = (unsigned)f2b(tile[c8*8+0][d]) | ((unsigned)f2b(tile[c8*8+1][d]) << 16);
        unsigned int w1 = (unsigned)f2b(tile[c8*8+2][d]) | ((unsigned)f2b(tile[c8*8+3][d]) << 16);
        unsigned int w2 = (unsigned)f2b(tile[c8*8+4][d]) | ((unsigned)f2b(tile[c8*8+5][d]) << 16);
        unsigned int w3 = (unsigned)f2b(tile[c8*8+6][d]) | ((unsigned)f2b(tile[c8*8+7][d]) << 16);
        uint4 pk = { w0, w1, w2, w3 };
        *(uint4*)(dst + (size_t)d * NN + c8 * 8) = pk;
    }
}

// ---------- staging helper: 64x64 bf16 tile -> padded LDS [64][72] ----------
__device__ __forceinline__ void stage_tile(unsigned short (*dst)[72],
                                           const unsigned short* __restrict__ src,
                                           int srcStride, int tid) {
#pragma unroll
    for (int h = 0; h < 2; ++h) {
        int cc = tid + h * 256;          // 512 chunks of 16B
        int row = cc >> 3, c8 = cc & 7;
        uint4 val = *(const uint4*)(src + (size_t)row * srcStride + c8 * 8);
        *(uint4*)&dst[row][c8 * 8] = val;
    }
}

// ---------- fused attention: per block = 64 Q-rows of one head ----------
__global__ __launch_bounds__(256, 4) void attn(
        const unsigned short* __restrict__ Qw, const unsigned short* __restrict__ Kw,
        const unsigned short* __restrict__ Vtw,
        float* __restrict__ outp, float* __restrict__ score) {
    __shared__ unsigned short qa[64][72], kb[64][72], vt[64][72], pl[64][72];
    __shared__ float lsum[64];

    int tid = threadIdx.x;
    int bh = blockIdx.x & 31, qt = blockIdx.x >> 5;   // blockIdx%8 == bh%8 -> XCD-local heads
    int i0 = qt * 64;
    const unsigned short* Qh = Qw + ((size_t)bh * NN + i0) * DD;
    const unsigned short* Kh = Kw + (size_t)bh * NN * DD;
    const unsigned short* Vh = Vtw + (size_t)bh * DD * NN;
    float* scoreH = score + (size_t)bh * NN * NN + (size_t)i0 * NN;
    float* outH   = outp  + ((size_t)bh * NN + i0) * DD;

    int lane = tid & 63, wave = tid >> 6;
    int l4 = lane & 15, quad = lane >> 4;
    int row0 = wave * 16;

    stage_tile(qa, Qh, DD, tid);

    // ---- phase 1: row sums of exp(0.5 + sim/128) ----
    float psum[4] = {0.f, 0.f, 0.f, 0.f};
    for (int kt = 0; kt < 32; ++kt) {
        __syncthreads();
        stage_tile(kb, Kh + (size_t)kt * 64 * DD, DD, tid);
        __syncthreads();
        bf16x8 a0 = *(const bf16x8*)&qa[row0 + l4][quad * 8];
        bf16x8 a1 = *(const bf16x8*)&qa[row0 + l4][32 + quad * 8];
#pragma unroll
        for (int nb = 0; nb < 4; ++nb) {
            bf16x8 b0 = *(const bf16x8*)&kb[nb * 16 + l4][quad * 8];
            bf16x8 b1 = *(const bf16x8*)&kb[nb * 16 + l4][32 + quad * 8];
            f32x4 acc = {0.f, 0.f, 0.f, 0.f};
            acc = __builtin_amdgcn_mfma_f32_16x16x32_bf16(a0, b0, acc, 0, 0, 0);
            acc = __builtin_amdgcn_mfma_f32_16x16x32_bf16(a1, b1, acc, 0, 0, 0);
#pragma unroll
            for (int r = 0; r < 4; ++r)
                psum[r] += __expf(fmaf(acc[r], 0.0078125f, 0.5f));
        }
    }
#pragma unroll
    for (int r = 0; r < 4; ++r) {
#pragma unroll
        for (int m = 1; m < 16; m <<= 1) psum[r] += __shfl_xor(psum[r], m, 64);
    }
    if (l4 == 0) {
#pragma unroll
        for (int r = 0; r < 4; ++r) lsum[row0 + quad * 4 + r] = psum[r];
    }
    __syncthreads();
    float rinv[4];
#pragma unroll
    for (int r = 0; r < 4; ++r) rinv[r] = 1.0f / lsum[row0 + quad * 4 + r];

    // ---- phase 2: recompute, write score, accumulate O = P*V ----
    f32x4 o[4];
#pragma unroll
    for (int nb = 0; nb < 4; ++nb) o[nb] = (f32x4){0.f, 0.f, 0.f, 0.f};

    for (int kt = 0; kt < 32; ++kt) {
        __syncthreads();
        stage_tile(kb, Kh + (size_t)kt * 64 * DD, DD, tid);
        stage_tile(vt, Vh + kt * 64, NN, tid);
        __syncthreads();
        bf16x8 a0 = *(const bf16x8*)&qa[row0 + l4][quad * 8];
        bf16x8 a1 = *(const bf16x8*)&qa[row0 + l4][32 + quad * 8];
#pragma unroll
        for (int nb = 0; nb < 4; ++nb) {
            bf16x8 b0 = *(const bf16x8*)&kb[nb * 16 + l4][quad * 8];
            bf16x8 b1 = *(const bf16x8*)&kb[nb * 16 + l4][32 + quad * 8];
            f32x4 acc = {0.f, 0.f, 0.f, 0.f};
            acc = __builtin_amdgcn_mfma_f32_16x16x32_bf16(a0, b0, acc, 0, 0, 0);
            acc = __builtin_amdgcn_mfma_f32_16x16x32_bf16(a1, b1, acc, 0, 0, 0);
#pragma unroll
            for (int r = 0; r < 4; ++r) {
                float p = __expf(fmaf(acc[r], 0.0078125f, 0.5f)) * rinv[r];
                int rr = row0 + quad * 4 + r;
                __builtin_nontemporal_store(p, &scoreH[(size_t)rr * NN + kt * 64 + nb * 16 + l4]);
                pl[rr][nb * 16 + l4] = f2b(p);
            }
        }
        __syncthreads();
        bf16x8 p0 = *(const bf16x8*)&pl[row0 + l4][quad * 8];
        bf16x8 p1 = *(const bf16x8*)&pl[row0 + l4][32 + quad * 8];
#pragma unroll
        for (int nb = 0; nb < 4; ++nb) {
            bf16x8 v0 = *(const bf16x8*)&vt[nb * 16 + l4][quad * 8];
            bf16x8 v1 = *(const bf16x8*)&vt[nb * 16 + l4][32 + quad * 8];
            o[nb] = __builtin_amdgcn_mfma_f32_16x16x32_bf16(p0, v0, o[nb], 0, 0, 0);
            o[nb] = __builtin_amdgcn_mfma_f32_16x16x32_bf16(p1, v1, o[nb], 0, 0, 0);
        }
    }
#pragma unroll
    for (int nb = 0; nb < 4; ++nb) {
#pragma unroll
        for (int r = 0; r < 4; ++r)
            outH[(size_t)(row0 + quad * 4 + r) * DD + nb * 16 + l4] = o[nb][r];
    }
}

extern "C" void kernel_launch(void* const* d_in, const int* in_sizes, int n_in,
                              void* d_out, int out_size, void* d_ws, size_t ws_size,
                              hipStream_t stream) {
    const float* q = (const float*)d_in[0];
    const float* k = (const float*)d_in[1];
    const float* v = (const float*)d_in[2];
    float* outp  = (float*)d_out;
    float* score = outp + (size_t)4 * 8 * 2048 * 64;     // out first, then score

    unsigned short* Qw  = (unsigned short*)d_ws;          // bf16(2q-1) [bh][n][d]
    unsigned short* Kw  = Qw + (size_t)4 * 8 * 2048 * 64; // bf16(2k-1) [bh][n][d]
    unsigned short* Vtw = Kw + (size_t)4 * 8 * 2048 * 64; // bf16(v)    [bh][d][n]

    prep_qk<<<4096, 256, 0, stream>>>((const float4*)q, (const float4*)k,
                                      (ushort4*)Qw, (ushort4*)Kw);
    prep_v<<<1024, 256, 0, stream>>>(v, Vtw);
    attn<<<1024, 256, 0, stream>>>(Qw, Kw, Vtw, outp, score);
}